// Round 10
// baseline (76.640 us; speedup 1.0000x reference)
//
#include <hip/hip_runtime.h>
#include <math.h>

// Problem constants: N=8, S=4096, C=2, V=128, K=512
#define N_TOK    32768
#define C_CH     2
#define V_DIM    128
#define K_CODES  512
#define TPB      64          // tokens per block (4 tiles of 16)
#define CAND_CAP 768
#define BAND     4.0e-3f     // >= 2*beta; beta = rigorous bf16 screen bound

typedef short     bf16v8 __attribute__((ext_vector_type(8)));
typedef float     f32x4  __attribute__((ext_vector_type(4)));
typedef unsigned  u32x4  __attribute__((ext_vector_type(4)));

// round-to-nearest-even fp32 -> bf16
__device__ inline unsigned f2bf(float f) {
    unsigned u = __float_as_uint(f);
    return (u + 0x7FFFu + ((u >> 16) & 1u)) >> 16;
}
__device__ inline unsigned mapf(float d) {          // order-preserving f32->u32
    unsigned u = __float_as_uint(d);
    return ((int)u < 0) ? ~u : (u | 0x80000000u);
}
__device__ inline float unmapf(unsigned u) {
    return __uint_as_float((u & 0x80000000u) ? (u & 0x7FFFFFFFu) : ~u);
}

// ---------------------------------------------------------------------------
// Kernel 0: ||e||^2 (fp32), zero hist, build PLAIN row-major bf16 e-image
// (img[row][v] as 16x16B slots; no swizzle — B-frags are read straight to
// VGPRs in vq_main, no LDS staging anywhere).
// ---------------------------------------------------------------------------
__global__ __launch_bounds__(64) void vq_prep(const float* __restrict__ emb,
                                              float* __restrict__ e_sq,
                                              unsigned int* __restrict__ hist,
                                              unsigned char* __restrict__ img) {
    const int row  = blockIdx.x;          // c*512 + k
    const int lane = threadIdx.x;
    const float a = emb[(size_t)row * V_DIM + lane];
    const float b = emb[(size_t)row * V_DIM + 64 + lane];
    float s = a * a + b * b;
#pragma unroll
    for (int off = 32; off; off >>= 1) s += __shfl_down(s, off);
    if (lane == 0) {
        e_sq[row] = s;
        if (row < K_CODES) hist[row] = 0u;
    }
    if (lane < 16) {
        const float* src = emb + (size_t)row * V_DIM + lane * 8;
        u32x4 val;
#pragma unroll
        for (int q = 0; q < 4; ++q)
            val[q] = f2bf(src[2 * q]) | (f2bf(src[2 * q + 1]) << 16);
        *reinterpret_cast<u32x4*>(img + ((size_t)row * 16 + lane) * 16) = val;
    }
}

// ---------------------------------------------------------------------------
// Kernel 1: main VQ. grid (512, 2), block 256 (4 waves), ~2 blocks/CU.
// Wave w holds B-fragments for its PRIVATE 128 codes in 128 VGPRs (loaded
// once). 4 token-tiles of 16; x prefetched one tile ahead; 32 MFMA/tile/wave;
// per-token screened min via regs+shfl+LDS atomicMin; register re-scan for
// band candidates; exact fp32 phase (16-lane groups) decides argmin.
// NO LDS staging, NO global_load_lds, NO global atomics.
// ---------------------------------------------------------------------------
__global__ __launch_bounds__(256, 2) void vq_main(const float* __restrict__ x0,
                                                  const float* __restrict__ emb,
                                                  const float* __restrict__ e_sq,
                                                  const unsigned char* __restrict__ img,
                                                  unsigned short* __restrict__ idx16,
                                                  float* __restrict__ out0,
                                                  float* __restrict__ out1,
                                                  float* __restrict__ out2) {
    __shared__ float xx_s[TPB];
    __shared__ unsigned int dmin_s[TPB];
    __shared__ unsigned long long best_s[TPB];
    __shared__ unsigned int cand[CAND_CAP];
    __shared__ int cand_n;

    const int c    = blockIdx.y;
    const int gt0  = blockIdx.x * TPB;
    const int t    = threadIdx.x;
    const int lane = t & 63;
    const int w    = t >> 6;
    const int l15  = lane & 15;
    const int l4   = lane >> 4;

    if (t < TPB) { dmin_s[t] = 0xFFFFFFFFu; best_s[t] = ~0ull; }
    if (t == 0) cand_n = 0;

    // ---- B fragments for this wave's 128 codes: 128 VGPRs, loaded once ----
    u32x4 Bf[8][4];
    {
        const unsigned char* imgc = img + (size_t)(c * K_CODES + w * 128) * 256;
#pragma unroll
        for (int ct = 0; ct < 8; ++ct)
#pragma unroll
            for (int kk = 0; kk < 4; ++kk)
                Bf[ct][kk] = *reinterpret_cast<const u32x4*>(
                    imgc + (size_t)(ct * 16 + l15) * 256 + (kk * 4 + l4) * 16);
    }
    float esq_r[8];
#pragma unroll
    for (int ct = 0; ct < 8; ++ct)
        esq_r[ct] = e_sq[c * K_CODES + w * 128 + ct * 16 + l15];

    __syncthreads();   // init (dmin/best/cand_n) visible before first atomicMin

    f32x4 raw[8];
    auto LOADX = [&](int tile_) {
        const float* xp = x0 + ((size_t)(gt0 + tile_ * 16 + l15) * C_CH + c) * V_DIM
                        + l4 * 8;
#pragma unroll
        for (int kk = 0; kk < 4; ++kk) {
            raw[2 * kk]     = *reinterpret_cast<const f32x4*>(xp + kk * 32);
            raw[2 * kk + 1] = *reinterpret_cast<const f32x4*>(xp + kk * 32 + 4);
        }
    };

    LOADX(0);
#pragma unroll
    for (int tile = 0; tile < 4; ++tile) {
        // ---- convert raw -> A frags (RNE) + ||x||^2 partial ----
        u32x4 A[4];
        float part = 0.f;
#pragma unroll
        for (int kk = 0; kk < 4; ++kk) {
            const f32x4 lo = raw[2 * kk], hi = raw[2 * kk + 1];
            u32x4 v;
            v[0] = f2bf(lo[0]) | (f2bf(lo[1]) << 16);
            v[1] = f2bf(lo[2]) | (f2bf(lo[3]) << 16);
            v[2] = f2bf(hi[0]) | (f2bf(hi[1]) << 16);
            v[3] = f2bf(hi[2]) | (f2bf(hi[3]) << 16);
            A[kk] = v;
#pragma unroll
            for (int z = 0; z < 4; ++z) {
                part = fmaf(lo[z], lo[z], part);
                part = fmaf(hi[z], hi[z], part);
            }
        }
        part += __shfl_xor(part, 16);
        part += __shfl_xor(part, 32);
        if (w == 0 && l4 == 0) xx_s[tile * 16 + l15] = part;

        if (tile < 3) LOADX(tile + 1);   // prefetch next tile (overwrites raw)

        // ---- 32 MFMA against resident Bf ----
        f32x4 acc[8];
#pragma unroll
        for (int ct = 0; ct < 8; ++ct) acc[ct] = (f32x4){0.f, 0.f, 0.f, 0.f};
#pragma unroll
        for (int kk = 0; kk < 4; ++kk)
#pragma unroll
            for (int ct = 0; ct < 8; ++ct)
                acc[ct] = __builtin_amdgcn_mfma_f32_16x16x32_bf16(
                    __builtin_bit_cast(bf16v8, A[kk]),
                    __builtin_bit_cast(bf16v8, Bf[ct][kk]), acc[ct], 0, 0, 0);

        // ---- screened distances + per-token min ----
#pragma unroll
        for (int ct = 0; ct < 8; ++ct)
#pragma unroll
            for (int r = 0; r < 4; ++r)
                acc[ct][r] = fmaf(-2.f, acc[ct][r], esq_r[ct]);
#pragma unroll
        for (int r = 0; r < 4; ++r) {
            float v = acc[0][r];
#pragma unroll
            for (int ct = 1; ct < 8; ++ct) v = fminf(v, acc[ct][r]);
#pragma unroll
            for (int s = 1; s < 16; s <<= 1) v = fminf(v, __shfl_xor(v, s));
            if (l15 == 0)
                atomicMin(&dmin_s[tile * 16 + l4 * 4 + r], mapf(v));
        }
        __syncthreads();   // all waves' mins for this tile visible

        // ---- register re-scan: candidates within BAND ----
#pragma unroll
        for (int r = 0; r < 4; ++r) {
            const int tok = tile * 16 + l4 * 4 + r;
            const float thr = unmapf(dmin_s[tok]) + BAND;
#pragma unroll
            for (int ct = 0; ct < 8; ++ct) {
                if (acc[ct][r] <= thr) {
                    const int k = w * 128 + ct * 16 + l15;
                    const int pos = atomicAdd(&cand_n, 1);
                    if (pos < CAND_CAP)
                        cand[pos] = ((unsigned)tok << 9) | (unsigned)k;
                }
            }
        }
    }
    __syncthreads();   // cand list final

    // ---- exact fp32 phase: one candidate per 16-lane group ----
    {
        const int nc = cand_n < CAND_CAP ? cand_n : CAND_CAP;
        const int g  = t >> 4;      // 16 groups
        const int gl = t & 15;
        for (int i = g; i < nc; i += 16) {
            const unsigned key = cand[i];
            const int tok = key >> 9;
            const int kc  = key & (K_CODES - 1);
            const float* xg = x0 + ((size_t)(gt0 + tok) * C_CH + c) * V_DIM + gl * 8;
            const float* eg = emb + ((size_t)c * K_CODES + kc) * V_DIM + gl * 8;
            const f32x4 xa = *reinterpret_cast<const f32x4*>(xg);
            const f32x4 xb = *reinterpret_cast<const f32x4*>(xg + 4);
            const f32x4 ea = *reinterpret_cast<const f32x4*>(eg);
            const f32x4 eb = *reinterpret_cast<const f32x4*>(eg + 4);
            float d8 = 0.f;
#pragma unroll
            for (int z = 0; z < 4; ++z) {
                d8 = fmaf(xa[z], ea[z], d8);
                d8 = fmaf(xb[z], eb[z], d8);
            }
#pragma unroll
            for (int s = 1; s < 16; s <<= 1) d8 += __shfl_xor(d8, s);
            if (gl == 0) {
                const float d = fmaf(-2.f, d8, e_sq[c * K_CODES + kc]);
                atomicMin(&best_s[tok],
                          ((unsigned long long)mapf(d) << 32) | (unsigned)kc);
            }
        }
    }
    __syncthreads();

    // ---- out1/out2/index ----
    if (t < TPB) {
        const unsigned long long b = best_s[t];
        const int k = (int)(b & (unsigned)(K_CODES - 1));
        const float d = unmapf((unsigned)(b >> 32));
        const float o12 = xx_s[t] + d;
        const size_t oi = (size_t)(gt0 + t) * C_CH + c;
        out1[oi] = o12;
        out2[oi] = o12;
        idx16[oi] = (unsigned short)k;
    }

    // ---- out0: (e - x) + x, coalesced ----
#pragma unroll
    for (int p = 0; p < 8; ++p) {
        const int tok = p * 8 + (t >> 5);
        const int v4  = t & 31;
        const int k   = (int)(best_s[tok] & (unsigned long long)(K_CODES - 1));
        const f32x4 ev = *reinterpret_cast<const f32x4*>(
            emb + ((size_t)c * K_CODES + k) * V_DIM + v4 * 4);
        const f32x4 xv = *reinterpret_cast<const f32x4*>(
            x0 + ((size_t)(gt0 + tok) * C_CH + c) * V_DIM + v4 * 4);
        f32x4 ov;
#pragma unroll
        for (int z = 0; z < 4; ++z) ov[z] = (ev[z] - xv[z]) + xv[z];
        *reinterpret_cast<f32x4*>(
            out0 + ((size_t)(gt0 + tok) * C_CH + c) * V_DIM + v4 * 4) = ov;
    }
}

// ---------------------------------------------------------------------------
// Kernel 2: histogram from the index array (LDS atomics; 16 blocks).
// ---------------------------------------------------------------------------
__global__ __launch_bounds__(256) void vq_hist(const unsigned short* __restrict__ idx16,
                                               unsigned int* __restrict__ hist) {
    __shared__ unsigned int h[K_CODES];
    const int t = threadIdx.x;
    h[t] = 0u; h[t + 256] = 0u;
    __syncthreads();
    const int base = blockIdx.x * 4096;
#pragma unroll
    for (int j = 0; j < 16; ++j)
        atomicAdd(&h[idx16[base + j * 256 + t]], 1u);
    __syncthreads();
    if (h[t])       atomicAdd(&hist[t],       h[t]);
    if (h[t + 256]) atomicAdd(&hist[t + 256], h[t + 256]);
}

// ---------------------------------------------------------------------------
// Kernel 3: entropy over the 512-bin histogram (prob = hist / 32768).
// ---------------------------------------------------------------------------
__global__ __launch_bounds__(512) void vq_entropy(const unsigned int* __restrict__ hist,
                                                  float* __restrict__ ent) {
    const int t = threadIdx.x;
    float v = 0.f;
    const unsigned int h = hist[t];
    if (h > 0u) {
        const float p = (float)h * (1.0f / 32768.0f);
        v = p * logf(p);
    }
#pragma unroll
    for (int off = 32; off; off >>= 1) v += __shfl_down(v, off);
    __shared__ float s[8];
    if ((t & 63) == 0) s[t >> 6] = v;
    __syncthreads();
    if (t == 0) {
        float tot = 0.f;
#pragma unroll
        for (int i = 0; i < 8; ++i) tot += s[i];
        ent[0] = -tot;
    }
}

// ---------------------------------------------------------------------------
extern "C" void kernel_launch(void* const* d_in, const int* in_sizes, int n_in,
                              void* d_out, int out_size, void* d_ws, size_t ws_size,
                              hipStream_t stream) {
    const float* x0  = (const float*)d_in[0];   // (N,S,C,V) fp32
    const float* emb = (const float*)d_in[1];   // (C,K,V)   fp32

    float*          e_sq  = (float*)d_ws;                            // 4 KB
    unsigned int*   hist  = (unsigned int*)((char*)d_ws + 4096);     // 2 KB
    unsigned char*  img   = (unsigned char*)d_ws + 8192;             // 256 KB bf16
    unsigned short* idx16 = (unsigned short*)((char*)d_ws + 8192 + 262144); // 128 KB

    float* out0 = (float*)d_out;
    float* out1 = out0 + (size_t)N_TOK * C_CH * V_DIM;
    float* out2 = out1 + (size_t)N_TOK * C_CH;
    float* ent  = out2 + (size_t)N_TOK * C_CH;

    vq_prep<<<C_CH * K_CODES, 64, 0, stream>>>(emb, e_sq, hist, img);
    vq_main<<<dim3(N_TOK / TPB, C_CH), 256, 0, stream>>>(x0, emb, e_sq, img, idx16,
                                                         out0, out1, out2);
    vq_hist<<<16, 256, 0, stream>>>(idx16, hist);
    vq_entropy<<<1, K_CODES, 0, stream>>>(hist, ent);
}

// Round 11
// 76.492 us; speedup vs baseline: 1.0019x; 1.0019x over previous
//
#include <hip/hip_runtime.h>
#include <math.h>

// Problem constants: N=8, S=4096, C=2, V=128, K=512
#define N_TOK    32768
#define C_CH     2
#define V_DIM    128
#define K_CODES  512
#define TPB      64          // tokens per block (4 tiles of 16)
#define WCAP     128         // per-wave candidate list capacity
#define BAND     4.0e-3f     // >= 2*beta; beta = rigorous bf16 screen bound

typedef short     bf16v8 __attribute__((ext_vector_type(8)));
typedef float     f32x4  __attribute__((ext_vector_type(4)));
typedef unsigned  u32x4  __attribute__((ext_vector_type(4)));

// round-to-nearest-even fp32 -> bf16
__device__ inline unsigned f2bf(float f) {
    unsigned u = __float_as_uint(f);
    return (u + 0x7FFFu + ((u >> 16) & 1u)) >> 16;
}
__device__ inline unsigned mapf(float d) {          // order-preserving f32->u32
    unsigned u = __float_as_uint(d);
    return ((int)u < 0) ? ~u : (u | 0x80000000u);
}
__device__ inline float unmapf(unsigned u) {
    return __uint_as_float((u & 0x80000000u) ? (u & 0x7FFFFFFFu) : ~u);
}

// ---------------------------------------------------------------------------
// Kernel 0: ||e||^2 (fp32), zero hist, build plain row-major bf16 e-image
// (img[row] = 16 slots of 16B; read straight into VGPR B-fragments).
// ---------------------------------------------------------------------------
__global__ __launch_bounds__(64) void vq_prep(const float* __restrict__ emb,
                                              float* __restrict__ e_sq,
                                              unsigned int* __restrict__ hist,
                                              unsigned char* __restrict__ img) {
    const int row  = blockIdx.x;          // c*512 + k
    const int lane = threadIdx.x;
    const float a = emb[(size_t)row * V_DIM + lane];
    const float b = emb[(size_t)row * V_DIM + 64 + lane];
    float s = a * a + b * b;
#pragma unroll
    for (int off = 32; off; off >>= 1) s += __shfl_down(s, off);
    if (lane == 0) {
        e_sq[row] = s;
        if (row < K_CODES) hist[row] = 0u;
    }
    if (lane < 16) {
        const float* src = emb + (size_t)row * V_DIM + lane * 8;
        u32x4 val;
#pragma unroll
        for (int q = 0; q < 4; ++q)
            val[q] = f2bf(src[2 * q]) | (f2bf(src[2 * q + 1]) << 16);
        *reinterpret_cast<u32x4*>(img + ((size_t)row * 16 + lane) * 16) = val;
    }
}

// ---------------------------------------------------------------------------
// Kernel 1: main VQ. grid (512, 2), block 256 (4 waves). Wave-autonomous:
// each wave owns 128 codes (B-frags resident in 128 VGPRs), screens all 64
// tokens with ZERO barriers (threshold read from dmin_s WITHOUT sync is a
// monotone over-estimate -> candidate superset -> exact phase still exact),
// then runs its own exact fp32 phase on its private candidate list.
// Only 2 block barriers total (post-init, pre-epilogue).
// ---------------------------------------------------------------------------
__global__ __launch_bounds__(256, 2) void vq_main(const float* __restrict__ x0,
                                                  const float* __restrict__ emb,
                                                  const float* __restrict__ e_sq,
                                                  const unsigned char* __restrict__ img,
                                                  unsigned int* __restrict__ hist,
                                                  float* __restrict__ out0,
                                                  float* __restrict__ out1,
                                                  float* __restrict__ out2) {
    __shared__ float xx_s[TPB];
    __shared__ unsigned int dmin_s[TPB];
    __shared__ unsigned long long best_s[TPB];
    __shared__ unsigned int cand_w[4][WCAP];
    __shared__ int cnt_w[4];

    const int c    = blockIdx.y;
    const int gt0  = blockIdx.x * TPB;
    const int t    = threadIdx.x;
    const int lane = t & 63;
    const int w    = t >> 6;
    const int l15  = lane & 15;
    const int l4   = lane >> 4;

    if (t < TPB) { dmin_s[t] = 0xFFFFFFFFu; best_s[t] = ~0ull; }
    if (t < 4) cnt_w[t] = 0;

    // ---- B fragments: this wave's 128 codes, 128 VGPRs, loaded once ----
    u32x4 Bf[8][4];
    {
        const unsigned char* imgc = img + (size_t)(c * K_CODES + w * 128) * 256;
#pragma unroll
        for (int ct = 0; ct < 8; ++ct)
#pragma unroll
            for (int kk = 0; kk < 4; ++kk)
                Bf[ct][kk] = *reinterpret_cast<const u32x4*>(
                    imgc + (size_t)(ct * 16 + l15) * 256 + (kk * 4 + l4) * 16);
    }
    float esq_r[8];
#pragma unroll
    for (int ct = 0; ct < 8; ++ct)
        esq_r[ct] = e_sq[c * K_CODES + w * 128 + ct * 16 + l15];

    __syncthreads();   // init visible before any wave's first atomicMin/push

    f32x4 raw[8];
    auto LOADX = [&](int tile_) {
        const float* xp = x0 + ((size_t)(gt0 + tile_ * 16 + l15) * C_CH + c) * V_DIM
                        + l4 * 8;
#pragma unroll
        for (int kk = 0; kk < 4; ++kk) {
            raw[2 * kk]     = *reinterpret_cast<const f32x4*>(xp + kk * 32);
            raw[2 * kk + 1] = *reinterpret_cast<const f32x4*>(xp + kk * 32 + 4);
        }
    };

    LOADX(0);
#pragma unroll
    for (int tile = 0; tile < 4; ++tile) {
        // ---- convert raw -> A frags (RNE) + ||x||^2 partial ----
        u32x4 A[4];
        float part = 0.f;
#pragma unroll
        for (int kk = 0; kk < 4; ++kk) {
            const f32x4 lo = raw[2 * kk], hi = raw[2 * kk + 1];
            u32x4 v;
            v[0] = f2bf(lo[0]) | (f2bf(lo[1]) << 16);
            v[1] = f2bf(lo[2]) | (f2bf(lo[3]) << 16);
            v[2] = f2bf(hi[0]) | (f2bf(hi[1]) << 16);
            v[3] = f2bf(hi[2]) | (f2bf(hi[3]) << 16);
            A[kk] = v;
#pragma unroll
            for (int z = 0; z < 4; ++z) {
                part = fmaf(lo[z], lo[z], part);
                part = fmaf(hi[z], hi[z], part);
            }
        }
        part += __shfl_xor(part, 16);
        part += __shfl_xor(part, 32);
        if (w == 0 && l4 == 0) xx_s[tile * 16 + l15] = part;

        if (tile < 3) LOADX(tile + 1);   // prefetch next tile

        // ---- 32 MFMA against resident Bf (8 independent chains) ----
        f32x4 acc[8];
#pragma unroll
        for (int ct = 0; ct < 8; ++ct) acc[ct] = (f32x4){0.f, 0.f, 0.f, 0.f};
#pragma unroll
        for (int kk = 0; kk < 4; ++kk)
#pragma unroll
            for (int ct = 0; ct < 8; ++ct)
                acc[ct] = __builtin_amdgcn_mfma_f32_16x16x32_bf16(
                    __builtin_bit_cast(bf16v8, A[kk]),
                    __builtin_bit_cast(bf16v8, Bf[ct][kk]), acc[ct], 0, 0, 0);

        // ---- screened distances ----
#pragma unroll
        for (int ct = 0; ct < 8; ++ct)
#pragma unroll
            for (int r = 0; r < 4; ++r)
                acc[ct][r] = fmaf(-2.f, acc[ct][r], esq_r[ct]);

        // ---- per-token wave-min -> LDS atomicMin (no barrier) ----
#pragma unroll
        for (int r = 0; r < 4; ++r) {
            float v = acc[0][r];
#pragma unroll
            for (int ct = 1; ct < 8; ++ct) v = fminf(v, acc[ct][r]);
#pragma unroll
            for (int s = 1; s < 16; s <<= 1) v = fminf(v, __shfl_xor(v, s));
            if (l15 == 0)
                atomicMin(&dmin_s[tile * 16 + l4 * 4 + r], mapf(v));
        }

        // ---- unsynchronized threshold read + register re-scan ----
        // (stale dmin >= global min -> threshold over-estimate -> candidate
        //  SUPERSET -> exact phase still decides correctly)
#pragma unroll
        for (int r = 0; r < 4; ++r) {
            const int tok = tile * 16 + l4 * 4 + r;
            const float thr = unmapf(dmin_s[tok]) + BAND;
#pragma unroll
            for (int ct = 0; ct < 8; ++ct) {
                if (acc[ct][r] <= thr) {
                    const int k = w * 128 + ct * 16 + l15;
                    const int pos = atomicAdd(&cnt_w[w], 1);
                    if (pos < WCAP)
                        cand_w[w][pos] = ((unsigned)tok << 9) | (unsigned)k;
                }
            }
        }
    }

    // ---- per-wave exact fp32 phase (4 groups of 16 lanes) ----
    {
        const int cnt0 = cnt_w[w];               // same-wave LDS: ordered
        const int cnt  = cnt0 < WCAP ? cnt0 : WCAP;
        for (int i = l4; i < cnt; i += 4) {
            const unsigned key = cand_w[w][i];
            const int tok = key >> 9;
            const int kc  = key & (K_CODES - 1);
            const float* xg = x0 + ((size_t)(gt0 + tok) * C_CH + c) * V_DIM + l15 * 8;
            const float* eg = emb + ((size_t)c * K_CODES + kc) * V_DIM + l15 * 8;
            const f32x4 xa = *reinterpret_cast<const f32x4*>(xg);
            const f32x4 xb = *reinterpret_cast<const f32x4*>(xg + 4);
            const f32x4 ea = *reinterpret_cast<const f32x4*>(eg);
            const f32x4 eb = *reinterpret_cast<const f32x4*>(eg + 4);
            float d8 = 0.f;
#pragma unroll
            for (int z = 0; z < 4; ++z) {
                d8 = fmaf(xa[z], ea[z], d8);
                d8 = fmaf(xb[z], eb[z], d8);
            }
#pragma unroll
            for (int s = 1; s < 16; s <<= 1) d8 += __shfl_xor(d8, s);
            if (l15 == 0) {
                const float d = fmaf(-2.f, d8, e_sq[c * K_CODES + kc]);
                atomicMin(&best_s[tok],
                          ((unsigned long long)mapf(d) << 32) | (unsigned)kc);
            }
        }
    }
    __syncthreads();   // all waves' exact results in best_s

    // ---- out1/out2/hist ----
    if (t < TPB) {
        const unsigned long long b = best_s[t];
        const int k = (int)(b & (unsigned)(K_CODES - 1));
        const float d = unmapf((unsigned)(b >> 32));
        const float o12 = xx_s[t] + d;
        const size_t oi = (size_t)(gt0 + t) * C_CH + c;
        out1[oi] = o12;
        out2[oi] = o12;
        atomicAdd(&hist[k], 1u);
    }

    // ---- out0: (e - x) + x, coalesced ----
#pragma unroll
    for (int p = 0; p < 8; ++p) {
        const int tok = p * 8 + (t >> 5);
        const int v4  = t & 31;
        const int k   = (int)(best_s[tok] & (unsigned long long)(K_CODES - 1));
        const f32x4 ev = *reinterpret_cast<const f32x4*>(
            emb + ((size_t)c * K_CODES + k) * V_DIM + v4 * 4);
        const f32x4 xv = *reinterpret_cast<const f32x4*>(
            x0 + ((size_t)(gt0 + tok) * C_CH + c) * V_DIM + v4 * 4);
        f32x4 ov;
#pragma unroll
        for (int z = 0; z < 4; ++z) ov[z] = (ev[z] - xv[z]) + xv[z];
        *reinterpret_cast<f32x4*>(
            out0 + ((size_t)(gt0 + tok) * C_CH + c) * V_DIM + v4 * 4) = ov;
    }
}

// ---------------------------------------------------------------------------
// Kernel 2: entropy over the 512-bin histogram (prob = hist / 32768).
// ---------------------------------------------------------------------------
__global__ __launch_bounds__(512) void vq_entropy(const unsigned int* __restrict__ hist,
                                                  float* __restrict__ ent) {
    const int t = threadIdx.x;
    float v = 0.f;
    const unsigned int h = hist[t];
    if (h > 0u) {
        const float p = (float)h * (1.0f / 32768.0f);
        v = p * logf(p);
    }
#pragma unroll
    for (int off = 32; off; off >>= 1) v += __shfl_down(v, off);
    __shared__ float s[8];
    if ((t & 63) == 0) s[t >> 6] = v;
    __syncthreads();
    if (t == 0) {
        float tot = 0.f;
#pragma unroll
        for (int i = 0; i < 8; ++i) tot += s[i];
        ent[0] = -tot;
    }
}

// ---------------------------------------------------------------------------
extern "C" void kernel_launch(void* const* d_in, const int* in_sizes, int n_in,
                              void* d_out, int out_size, void* d_ws, size_t ws_size,
                              hipStream_t stream) {
    const float* x0  = (const float*)d_in[0];   // (N,S,C,V) fp32
    const float* emb = (const float*)d_in[1];   // (C,K,V)   fp32

    float*         e_sq = (float*)d_ws;                          // 4 KB
    unsigned int*  hist = (unsigned int*)((char*)d_ws + 4096);   // 2 KB
    unsigned char* img  = (unsigned char*)d_ws + 8192;           // 256 KB bf16

    float* out0 = (float*)d_out;
    float* out1 = out0 + (size_t)N_TOK * C_CH * V_DIM;
    float* out2 = out1 + (size_t)N_TOK * C_CH;
    float* ent  = out2 + (size_t)N_TOK * C_CH;

    vq_prep<<<C_CH * K_CODES, 64, 0, stream>>>(emb, e_sq, hist, img);
    vq_main<<<dim3(N_TOK / TPB, C_CH), 256, 0, stream>>>(x0, emb, e_sq, img, hist,
                                                         out0, out1, out2);
    vq_entropy<<<1, K_CODES, 0, stream>>>(hist, ent);
}